// Round 2
// baseline (391.301 us; speedup 1.0000x reference)
//
#include <hip/hip_runtime.h>
#include <hip/hip_fp16.h>

#define C 4096
#define NN 110
#define MPAD 112

typedef _Float16 f16x8 __attribute__((ext_vector_type(8)));
typedef float fx4 __attribute__((ext_vector_type(4)));

// ---------------------------------------------------------------------------
// prep1: A1[112][4096] = fp16(x), rows >=110 zeroed
// ---------------------------------------------------------------------------
__global__ void prep1_kernel(const float* __restrict__ x, _Float16* __restrict__ A1) {
    int idx = blockIdx.x * 256 + threadIdx.x;          // 0 .. 112*4096-1
    int n = idx >> 12;
    float v = (n < NN) ? x[idx] : 0.f;
    A1[idx] = (_Float16)v;
}

// ---------------------------------------------------------------------------
// mm: barrier-free wave-autonomous split-K GEMM.
// Cacc[0:110, 0:4096] += A16[0:112, :] @ fp16(B[:, 0:4096])  (B fp32 row-major,
// row stride C=4096; A fp16 row-major, row stride lda=K).
// Each wave owns a 16-col strip (n0) and a K-chunk (kch rows): A frags from
// L2-resident A1/A3, B streamed as scalar dwords (per-instr: 4 rows x 64B),
// fp32->fp16 cvt in VALU, mfma_f32_16x16x32_f16, fp32 atomicAdd epilogue.
// No LDS, no __syncthreads -> loads from the 2-deep register pipeline stay
// in flight across k-steps. wid = block*4 + wave; ntile = wid&255 (N/16=256),
// chunk = wid>>8.
// ---------------------------------------------------------------------------
__global__ __launch_bounds__(256, 2)
void mm_kernel(const _Float16* __restrict__ A, const float* __restrict__ B,
               float* __restrict__ Cacc, int lda, int kch) {
    const int t   = threadIdx.x;
    const int wid = blockIdx.x * 4 + (t >> 6);
    const int L   = t & 63;
    const int l15 = L & 15;
    const int q   = L >> 4;                    // quad 0..3
    const int n0  = (wid & 255) * 16;
    const int k0  = (wid >> 8) * kch;

    const _Float16* Ap = A + (size_t)l15 * lda + k0 + q * 8;
    const float*    Bp = B + (size_t)(k0 + q * 8) * C + n0 + l15;

    fx4 acc[7];
    #pragma unroll
    for (int mt = 0; mt < 7; ++mt) acc[mt] = (fx4){0.f, 0.f, 0.f, 0.f};

    float bv0[8], bv1[8];
    f16x8 av0[7], av1[7];

    auto loadB = [&](float (&bv)[8], int kk) {
        #pragma unroll
        for (int j = 0; j < 8; ++j) bv[j] = Bp[(size_t)(kk + j) * C];
    };
    auto loadA = [&](f16x8 (&av)[7], int kk) {
        #pragma unroll
        for (int mt = 0; mt < 7; ++mt)
            av[mt] = *(const f16x8*)(Ap + (size_t)(mt * 16) * lda + kk);
    };
    auto consume = [&](float (&bv)[8], f16x8 (&av)[7]) {
        f16x8 bf;
        #pragma unroll
        for (int j = 0; j < 8; ++j) bf[j] = (_Float16)bv[j];
        #pragma unroll
        for (int mt = 0; mt < 7; ++mt)
            acc[mt] = __builtin_amdgcn_mfma_f32_16x16x32_f16(av[mt], bf, acc[mt], 0, 0, 0);
    };

    loadB(bv0, 0);
    loadA(av0, 0);
    for (int k = 0; k < kch; k += 64) {          // kch is a multiple of 64
        loadB(bv1, k + 32);
        loadA(av1, k + 32);
        consume(bv0, av0);
        if (k + 64 < kch) {
            loadB(bv0, k + 64);
            loadA(av0, k + 64);
        }
        consume(bv1, av1);
    }

    // epilogue (C/D layout: col=lane&15, row=q*4+reg)
    #pragma unroll
    for (int mt = 0; mt < 7; ++mt) {
        #pragma unroll
        for (int r = 0; r < 4; ++r) {
            int row = mt * 16 + q * 4 + r;
            if (row < NN)
                atomicAdd(&Cacc[(size_t)row * C + n0 + l15], acc[mt][r]);
        }
    }
}

// ---------------------------------------------------------------------------
// agg: per 16-col tile, builds A3 = fp16([h+b2, aggr]) [112][8192]
// aggr[j,c] = sum_i mask[i,j]*(h[i,c]+b2[c]) / max(deg_j,1)
// ---------------------------------------------------------------------------
__global__ __launch_bounds__(256)
void agg_kernel(const float* __restrict__ h_raw, const int* __restrict__ adj,
                const float* __restrict__ b2, _Float16* __restrict__ A3) {
    __shared__ float hb[NN * 16];
    __shared__ unsigned long long mlo[NN], mhi[NN];
    __shared__ float degs[NN];
    const int t  = threadIdx.x;
    const int c0 = blockIdx.x * 16;

    // load h tile (+bias), emit A3 first half
    for (int idx = t; idx < NN * 16; idx += 256) {
        int n = idx >> 4, c = idx & 15;
        float v = h_raw[(size_t)n * C + c0 + c] + b2[c0 + c];
        hb[idx] = v;
        A3[(size_t)n * (2 * C) + c0 + c] = (_Float16)v;
    }
    // zero pad rows 110,111 (both halves of this c-tile)
    if (t < 64) {
        int n  = NN + (t >> 5);
        int hs = (t >> 4) & 1;
        int c  = t & 15;
        A3[(size_t)n * (2 * C) + hs * C + c0 + c] = (_Float16)0.f;
    }
    // mask bits + degree per target j
    if (t < NN) {
        int j = t;
        unsigned long long lo = 0, hi = 0;
        int dg = 0;
        for (int i = 0; i < 64; ++i) {
            int m = (adj[i * NN + j] != 0);
            lo |= ((unsigned long long)m) << i; dg += m;
        }
        for (int i = 64; i < NN; ++i) {
            int m = (adj[i * NN + j] != 0);
            hi |= ((unsigned long long)m) << (i - 64); dg += m;
        }
        mlo[j] = lo; mhi[j] = hi;
        degs[j] = (float)(dg > 0 ? dg : 1);
    }
    __syncthreads();
    // aggr -> A3 second half
    for (int idx = t; idx < NN * 16; idx += 256) {
        int j = idx >> 4, c = idx & 15;
        unsigned long long lo = mlo[j], hi = mhi[j];
        float a = 0.f;
        for (int i = 0; i < 64; ++i)
            if ((lo >> i) & 1) a += hb[i * 16 + c];
        for (int i = 64; i < NN; ++i)
            if ((hi >> (i - 64)) & 1) a += hb[i * 16 + c];
        A3[(size_t)j * (2 * C) + C + c0 + c] = (_Float16)(a / degs[j]);
    }
}

// ---------------------------------------------------------------------------
// fin: out[j,c] = sum_k Wl[j,k] * relu(z_raw[k,c]+b1[c]) + bl[j]
// grid (64 c-tiles, 28 j-groups of 4); Wl loads are wave-uniform (scalar).
// ---------------------------------------------------------------------------
__global__ __launch_bounds__(256)
void fin_kernel(const float* __restrict__ z_raw, const float* __restrict__ b1,
                const float* __restrict__ Wl, const float* __restrict__ bl,
                float* __restrict__ out) {
    __shared__ float zs[NN * 64];
    const int t  = threadIdx.x;
    const int c0 = blockIdx.x * 64;
    const int j  = blockIdx.y * 4 + (t >> 6);
    const int c  = t & 63;

    for (int idx = t; idx < NN * 64; idx += 256) {
        int k = idx >> 6, cc = idx & 63;
        float v = z_raw[(size_t)k * C + c0 + cc] + b1[c0 + cc];
        zs[idx] = fmaxf(v, 0.f);
    }
    __syncthreads();
    if (j < NN) {
        float a = bl[j];
        #pragma unroll 2
        for (int k = 0; k < NN; ++k)
            a += Wl[j * NN + k] * zs[k * 64 + c];
        out[(size_t)j * C + c0 + c] = a;
    }
}

// ---------------------------------------------------------------------------
extern "C" void kernel_launch(void* const* d_in, const int* in_sizes, int n_in,
                              void* d_out, int out_size, void* d_ws, size_t ws_size,
                              hipStream_t stream) {
    const float* x   = (const float*)d_in[0];
    const int*   adj = (const int*)d_in[1];
    const float* W2  = (const float*)d_in[2];
    const float* b2  = (const float*)d_in[3];
    const float* W1  = (const float*)d_in[4];
    const float* b1  = (const float*)d_in[5];
    const float* Wl  = (const float*)d_in[6];
    const float* bl  = (const float*)d_in[7];
    float* out = (float*)d_out;

    char* ws = (char*)d_ws;
    float*    h_raw = (float*)(ws);                    // 110*4096 f32
    float*    z_raw = (float*)(ws + 1802240);          // 110*4096 f32
    _Float16* A1    = (_Float16*)(ws + 3604480);       // 112*4096 f16
    _Float16* A3    = (_Float16*)(ws + 4521984);       // 112*8192 f16

    hipMemsetAsync(d_ws, 0, 3604480, stream);          // zero h_raw, z_raw
    prep1_kernel<<<(MPAD * C) / 256, 256, 0, stream>>>(x, A1);
    // mm1: K=4096, kch=512 -> 8 chunks x 256 ntiles = 2048 waves = 512 blocks
    mm_kernel<<<512, 256, 0, stream>>>(A1, W2, h_raw, C, 512);
    agg_kernel<<<C / 16, 256, 0, stream>>>(h_raw, adj, b2, A3);
    // mm2: K=8192, kch=1024 -> 8 chunks x 256 ntiles = 2048 waves = 512 blocks
    mm_kernel<<<512, 256, 0, stream>>>(A3, W1, z_raw, 2 * C, 1024);
    fin_kernel<<<dim3(C / 64, 28), 256, 0, stream>>>(z_raw, b1, Wl, bl, out);
}

// Round 3
// 386.235 us; speedup vs baseline: 1.0131x; 1.0131x over previous
//
#include <hip/hip_runtime.h>
#include <hip/hip_fp16.h>

#define C 4096
#define NN 110
#define MPAD 112
#define BN 64
#define BK 128
#define KCH 512

typedef _Float16 f16x8 __attribute__((ext_vector_type(8)));
typedef float fx4 __attribute__((ext_vector_type(4)));

#define AS_GLB __attribute__((address_space(1)))
#define AS_LDS __attribute__((address_space(3)))

// ---------------------------------------------------------------------------
// prep1: A1[112][4096] = fp16(x), rows >=110 zeroed
// ---------------------------------------------------------------------------
__global__ void prep1_kernel(const float* __restrict__ x, _Float16* __restrict__ A1) {
    int idx = blockIdx.x * 256 + threadIdx.x;          // 0 .. 112*4096-1
    int n = idx >> 12;
    float v = (n < NN) ? x[idx] : 0.f;
    A1[idx] = (_Float16)v;
}

// ---------------------------------------------------------------------------
// mm: Cacc[0:110, n] += A16[0:112, k0:k0+512] @ fp16(B[k0:k0+512, n])
// B fp32 row-major (row stride C), staged 128x64 fp32 per iter via
// global_load_lds (direct-to-LDS, no VGPRs -> compiler can't serialize the
// prefetch), double-buffered with ONE barrier per iter: the top barrier both
// drains the prefetch of buf and fences the previous iter's reads of buf^1.
// A fp16 is L2-resident (<=1.8MB); fragments read b128 straight from global.
// 4 waves: wave w owns cols n0+w*16..+15, all 7 m-tiles. fp32 atomicAdd out.
// LDS layout Bs[buf][row][col] (row=k within chunk), contiguous as required
// by global_load_lds lane ordering: instr j stages rows w*32+j*4+(L>>4),
// float4 col (L&15) -> base + lane*16B exactly.
// ---------------------------------------------------------------------------
__global__ __launch_bounds__(256)
void mm_kernel(const _Float16* __restrict__ A, const float* __restrict__ B,
               float* __restrict__ Cacc, int lda) {
    __shared__ float Bs[2][BK * BN];                   // 2 x 32 KB
    const int t   = threadIdx.x;
    const int w   = t >> 6;
    const int L   = t & 63;
    const int l15 = L & 15;
    const int q   = L >> 4;                            // quad 0..3
    const int n0  = blockIdx.x * BN;
    const int k0  = blockIdx.y * KCH;

    // per-lane global src for staging: row = w*32 + j*4 + (L>>4), col4 = L&15
    const float* gsrc = B + (size_t)(k0 + w * 32 + (L >> 4)) * C + n0 + (L & 15) * 4;

    auto stage = [&](int buf, int kc) {
        #pragma unroll
        for (int j = 0; j < 8; ++j) {
            const float* g = gsrc + (size_t)(kc + j * 4) * C;
            float* l = &Bs[buf][(w * 32 + j * 4) * BN];
            __builtin_amdgcn_global_load_lds((const AS_GLB void*)g, (AS_LDS void*)l,
                                             16, 0, 0);
        }
    };

    fx4 acc[7];
    #pragma unroll
    for (int mt = 0; mt < 7; ++mt) acc[mt] = (fx4){0.f, 0.f, 0.f, 0.f};

    stage(0, 0);
    #pragma unroll 1
    for (int kc = 0, buf = 0; kc < KCH; kc += BK, buf ^= 1) {
        __syncthreads();                               // buf staged; buf^1 free
        if (kc + BK < KCH) stage(buf ^ 1, kc + BK);    // prefetch overlaps compute
        const _Float16* Ap = A + (size_t)l15 * lda + k0 + kc + q * 8;
        #pragma unroll
        for (int s = 0; s < 4; ++s) {
            f16x8 bfrag;
            #pragma unroll
            for (int j = 0; j < 8; ++j)
                bfrag[j] = (_Float16)Bs[buf][(s * 32 + q * 8 + j) * BN + w * 16 + l15];
            #pragma unroll
            for (int mt = 0; mt < 7; ++mt) {
                f16x8 afrag = *(const f16x8*)(Ap + (size_t)(mt * 16) * lda + s * 32);
                acc[mt] = __builtin_amdgcn_mfma_f32_16x16x32_f16(afrag, bfrag,
                                                                 acc[mt], 0, 0, 0);
            }
        }
    }

    // epilogue (C/D layout: col=lane&15, row=q*4+reg)
    #pragma unroll
    for (int mt = 0; mt < 7; ++mt) {
        #pragma unroll
        for (int r = 0; r < 4; ++r) {
            int row = mt * 16 + q * 4 + r;
            if (row < NN)
                atomicAdd(&Cacc[(size_t)row * C + n0 + w * 16 + l15], acc[mt][r]);
        }
    }
}

// ---------------------------------------------------------------------------
// agg: per 16-col tile, builds A3 = fp16([h+b2, aggr]) [112][8192]
// aggr[j,c] = sum_i mask[i,j]*(h[i,c]+b2[c]) / max(deg_j,1)
// ---------------------------------------------------------------------------
__global__ __launch_bounds__(256)
void agg_kernel(const float* __restrict__ h_raw, const int* __restrict__ adj,
                const float* __restrict__ b2, _Float16* __restrict__ A3) {
    __shared__ float hb[NN * 16];
    __shared__ unsigned long long mlo[NN], mhi[NN];
    __shared__ float degs[NN];
    const int t  = threadIdx.x;
    const int c0 = blockIdx.x * 16;

    for (int idx = t; idx < NN * 16; idx += 256) {
        int n = idx >> 4, c = idx & 15;
        float v = h_raw[(size_t)n * C + c0 + c] + b2[c0 + c];
        hb[idx] = v;
        A3[(size_t)n * (2 * C) + c0 + c] = (_Float16)v;
    }
    if (t < 64) {
        int n  = NN + (t >> 5);
        int hs = (t >> 4) & 1;
        int c  = t & 15;
        A3[(size_t)n * (2 * C) + hs * C + c0 + c] = (_Float16)0.f;
    }
    if (t < NN) {
        int j = t;
        unsigned long long lo = 0, hi = 0;
        int dg = 0;
        for (int i = 0; i < 64; ++i) {
            int m = (adj[i * NN + j] != 0);
            lo |= ((unsigned long long)m) << i; dg += m;
        }
        for (int i = 64; i < NN; ++i) {
            int m = (adj[i * NN + j] != 0);
            hi |= ((unsigned long long)m) << (i - 64); dg += m;
        }
        mlo[j] = lo; mhi[j] = hi;
        degs[j] = (float)(dg > 0 ? dg : 1);
    }
    __syncthreads();
    for (int idx = t; idx < NN * 16; idx += 256) {
        int j = idx >> 4, c = idx & 15;
        unsigned long long lo = mlo[j], hi = mhi[j];
        float a = 0.f;
        #pragma unroll 2
        for (int i = 0; i < 64; ++i)
            a = fmaf((float)((lo >> i) & 1ull), hb[i * 16 + c], a);
        #pragma unroll 2
        for (int i = 64; i < NN; ++i)
            a = fmaf((float)((hi >> (i - 64)) & 1ull), hb[i * 16 + c], a);
        A3[(size_t)j * (2 * C) + C + c0 + c] = (_Float16)(a / degs[j]);
    }
}

// ---------------------------------------------------------------------------
// fin: out[j,c] = sum_k Wl[j,k] * relu(z_raw[k,c]+b1[c]) + bl[j]
// ---------------------------------------------------------------------------
__global__ __launch_bounds__(256)
void fin_kernel(const float* __restrict__ z_raw, const float* __restrict__ b1,
                const float* __restrict__ Wl, const float* __restrict__ bl,
                float* __restrict__ out) {
    __shared__ float zs[NN * 64];
    const int t  = threadIdx.x;
    const int c0 = blockIdx.x * 64;
    const int j  = blockIdx.y * 4 + (t >> 6);
    const int c  = t & 63;

    for (int idx = t; idx < NN * 64; idx += 256) {
        int k = idx >> 6, cc = idx & 63;
        float v = z_raw[(size_t)k * C + c0 + cc] + b1[c0 + cc];
        zs[idx] = fmaxf(v, 0.f);
    }
    __syncthreads();
    if (j < NN) {
        float a = bl[j];
        #pragma unroll 2
        for (int k = 0; k < NN; ++k)
            a += Wl[j * NN + k] * zs[k * 64 + c];
        out[(size_t)j * C + c0 + c] = a;
    }
}

// ---------------------------------------------------------------------------
extern "C" void kernel_launch(void* const* d_in, const int* in_sizes, int n_in,
                              void* d_out, int out_size, void* d_ws, size_t ws_size,
                              hipStream_t stream) {
    const float* x   = (const float*)d_in[0];
    const int*   adj = (const int*)d_in[1];
    const float* W2  = (const float*)d_in[2];
    const float* b2  = (const float*)d_in[3];
    const float* W1  = (const float*)d_in[4];
    const float* b1  = (const float*)d_in[5];
    const float* Wl  = (const float*)d_in[6];
    const float* bl  = (const float*)d_in[7];
    float* out = (float*)d_out;

    char* ws = (char*)d_ws;
    float*    h_raw = (float*)(ws);                    // 110*4096 f32
    float*    z_raw = (float*)(ws + 1802240);          // 110*4096 f32
    _Float16* A1    = (_Float16*)(ws + 3604480);       // 112*4096 f16
    _Float16* A3    = (_Float16*)(ws + 4521984);       // 112*8192 f16

    hipMemsetAsync(d_ws, 0, 3604480, stream);          // zero h_raw, z_raw
    prep1_kernel<<<(MPAD * C) / 256, 256, 0, stream>>>(x, A1);
    // mm1: K=4096 -> grid (4096/64, 4096/512) = (64, 8) = 512 blocks
    mm_kernel<<<dim3(C / BN, C / KCH), 256, 0, stream>>>(A1, W2, h_raw, C);
    agg_kernel<<<C / 16, 256, 0, stream>>>(h_raw, adj, b2, A3);
    // mm2: K=8192 -> grid (64, 16) = 1024 blocks
    mm_kernel<<<dim3(C / BN, (2 * C) / KCH), 256, 0, stream>>>(A3, W1, z_raw, 2 * C);
    fin_kernel<<<dim3(C / 64, 28), 256, 0, stream>>>(z_raw, b1, Wl, bl, out);
}